// Round 7
// baseline (105.723 us; speedup 1.0000x reference)
//
#include <hip/hip_runtime.h>
#include <hip/hip_fp16.h>
#include <math.h>

#define N_NODES 50000
#define N_EDGES 1600000
#define ET (N_EDGES + N_NODES)
#define F_OUT 64
#define F_IN 128
#define SLOPE 0.2f
#define BSHIFT 7                               // 128 nodes per bucket
#define BNODES 128
#define NBUCK ((N_NODES + BNODES - 1) >> BSHIFT)   // 391 buckets
#define CAP 4736                               // mean 4224 + 8 sigma
#define EPB 2048                               // edges per partition block
#define PBLOCKS ((ET + EPB - 1) / EPB)

typedef _Float16 half8 __attribute__((ext_vector_type(8)));
typedef _Float16 half4 __attribute__((ext_vector_type(4)));
typedef float f32x4 __attribute__((ext_vector_type(4)));

// ---------------- MFMA GEMM: xp(f16) = x @ W + attention logits (+bcur zero) ----------------
__global__ __launch_bounds__(256) void gemm_kernel(const float4* __restrict__ x4,
                                                   const float4* __restrict__ W4,
                                                   const float* __restrict__ a_src,
                                                   const float* __restrict__ a_dst,
                                                   _Float16* __restrict__ xph,
                                                   float* __restrict__ alpha_s,
                                                   float* __restrict__ alpha_d,
                                                   int* __restrict__ bcur) {
    __shared__ _Float16 xs[64][136];          // padded: row stride 272B
    __shared__ float    Wsh[F_IN * F_OUT];    // 32 KB
    int t = threadIdx.x;
    if (blockIdx.x == 0)
        for (int i = t; i < NBUCK; i += 256) bcur[i] = 0;
    int wave = t >> 6, lane = t & 63;
    int g = lane >> 4, c16 = lane & 15;

    // stage W (32KB) coalesced
#pragma unroll
    for (int i = 0; i < 8; ++i)
        ((float4*)Wsh)[t + i * 256] = W4[t + i * 256];
    // stage x rows -> fp16 LDS
    size_t rbase = (size_t)blockIdx.x * 64;
#pragma unroll
    for (int i = 0; i < 8; ++i) {
        int idx = t + i * 256;                 // over 64*32 float4
        int row = idx >> 5, c4 = idx & 31;
        size_t gr = rbase + row;
        if (gr >= N_NODES) gr = N_NODES - 1;
        float4 v = x4[gr * (F_IN / 4) + c4];
        half4 hv = { (_Float16)v.x, (_Float16)v.y, (_Float16)v.z, (_Float16)v.w };
        *(half4*)&xs[row][c4 * 4] = hv;
    }
    __syncthreads();

    // B fragments: lane holds W[k = kt*32 + g*8 + e][col = nt*16 + c16]
    half8 bw[4][4];
#pragma unroll
    for (int nt = 0; nt < 4; ++nt)
#pragma unroll
        for (int kt = 0; kt < 4; ++kt) {
            int col = nt * 16 + c16;
            int k0 = kt * 32 + g * 8;
#pragma unroll
            for (int e = 0; e < 8; ++e)
                bw[nt][kt][e] = (_Float16)Wsh[(k0 + e) * F_OUT + col];
        }

    // A fragments (same k map) + MFMA
    int r0 = wave * 16;
    half8 af[4];
#pragma unroll
    for (int kt = 0; kt < 4; ++kt)
        af[kt] = *(const half8*)&xs[r0 + c16][kt * 32 + g * 8];

    f32x4 acc[4];
#pragma unroll
    for (int nt = 0; nt < 4; ++nt) {
        acc[nt] = (f32x4){0.f, 0.f, 0.f, 0.f};
#pragma unroll
        for (int kt = 0; kt < 4; ++kt)
            acc[nt] = __builtin_amdgcn_mfma_f32_16x16x32_f16(af[kt], bw[nt][kt], acc[nt], 0, 0, 0);
    }

    // epilogue: D layout row=g*4+r, col=nt*16+c16
    int growbase = (int)rbase + r0 + g * 4;
#pragma unroll
    for (int nt = 0; nt < 4; ++nt) {
#pragma unroll
        for (int r = 0; r < 4; ++r) {
            int row = growbase + r;
            if (row < N_NODES)
                xph[(size_t)row * F_OUT + nt * 16 + c16] = (_Float16)acc[nt][r];
        }
    }
    float asl[4], adl[4];
#pragma unroll
    for (int nt = 0; nt < 4; ++nt) {
        asl[nt] = a_src[nt * 16 + c16];
        adl[nt] = a_dst[nt * 16 + c16];
    }
#pragma unroll
    for (int r = 0; r < 4; ++r) {
        float ps = 0.f, pd = 0.f;
#pragma unroll
        for (int nt = 0; nt < 4; ++nt) {
            ps = fmaf(acc[nt][r], asl[nt], ps);
            pd = fmaf(acc[nt][r], adl[nt], pd);
        }
#pragma unroll
        for (int off = 1; off < 16; off <<= 1) {
            ps += __shfl_xor(ps, off);
            pd += __shfl_xor(pd, off);
        }
        int row = growbase + r;
        if (c16 == 0 && row < N_NODES) { alpha_s[row] = ps; alpha_d[row] = pd; }
    }
}

// ---------------- partition: bucket-sorted packed records (s | d<<16), static bases ----------------
__global__ __launch_bounds__(256) void part_kernel(const int* __restrict__ ei,
                                                   int* __restrict__ bcur,
                                                   unsigned* __restrict__ rec) {
    __shared__ int lc[NBUCK];
    __shared__ int lbase[NBUCK];
    int t = threadIdx.x;
    for (int b = t; b < NBUCK; b += 256) lc[b] = 0;
    __syncthreads();
    int e0 = blockIdx.x * EPB;
#pragma unroll
    for (int k = 0; k < EPB / 256; ++k) {
        int e = e0 + k * 256 + t;
        if (e < ET) {
            int d = (e < N_EDGES) ? ei[N_EDGES + e] : e - N_EDGES;
            atomicAdd(&lc[d >> BSHIFT], 1);
        }
    }
    __syncthreads();
    for (int b = t; b < NBUCK; b += 256)
        lbase[b] = lc[b] ? (b * CAP + atomicAdd(&bcur[b], lc[b])) : 0;
    __syncthreads();
    for (int b = t; b < NBUCK; b += 256) lc[b] = 0;
    __syncthreads();
#pragma unroll
    for (int k = 0; k < EPB / 256; ++k) {
        int e = e0 + k * 256 + t;
        if (e < ET) {
            int s, d;
            if (e < N_EDGES) { s = ei[e]; d = ei[N_EDGES + e]; }
            else             { s = d = e - N_EDGES; }
            int b = d >> BSHIFT;
            int r = atomicAdd(&lc[b], 1);
            rec[lbase[b] + r] = (unsigned)s | ((unsigned)d << 16);
        }
    }
}

// ---------------- scan helper (8 waves) ----------------
__device__ __forceinline__ int block_incl_scan(int v, int t, int* wsum) {
    int lane = t & 63, wave = t >> 6;
#pragma unroll
    for (int off = 1; off < 64; off <<= 1) {
        int n = __shfl_up(v, off);
        if (lane >= off) v += n;
    }
    if (lane == 63) wsum[wave] = v;
    __syncthreads();
    int add = 0;
    for (int w = 0; w < wave; ++w) add += wsum[w];
    return v + add;
}

// ---------------- per-bucket CSR build + edge-weight precompute ----------------
__global__ __launch_bounds__(512) void csrb_kernel(const unsigned* __restrict__ rec,
                                                   const int* __restrict__ bcur,
                                                   const float* __restrict__ as,
                                                   const float* __restrict__ ad,
                                                   int* __restrict__ offsets,
                                                   int* __restrict__ counts,
                                                   unsigned* __restrict__ wcsr) {
    __shared__ unsigned lrec[CAP];            // 18.9 KB
    __shared__ int lcnt[BNODES], loff[BNODES], lcur[BNODES];
    __shared__ float adl[BNODES];
    __shared__ int wsum[8];
    int t = threadIdx.x;
    int b = blockIdx.x;
    int n0 = b << BSHIFT;
    int r0 = b * CAP;
    int cnt_b = bcur[b];
    if (t < BNODES) {
        lcnt[t] = 0; lcur[t] = 0;
        adl[t] = (n0 + t < N_NODES) ? ad[n0 + t] : 0.f;
    }
    for (int i = t; i < cnt_b; i += 512) lrec[i] = rec[r0 + i];
    __syncthreads();
    for (int i = t; i < cnt_b; i += 512)
        atomicAdd(&lcnt[(lrec[i] >> 16) & (BNODES - 1)], 1);
    __syncthreads();
    int v = (t < BNODES) ? lcnt[t] : 0;
    int incl = block_incl_scan(v, t, wsum);
    if (t < BNODES) {
        loff[t] = incl - v;
        if (n0 + t < N_NODES) { counts[n0 + t] = v; offsets[n0 + t] = r0 + incl - v; }
    }
    __syncthreads();
    for (int i = t; i < cnt_b; i += 512) {
        unsigned u = lrec[i];
        int dl = (u >> 16) & (BNODES - 1);
        int s = u & 0xFFFFu;
        float ev = as[s] + adl[dl];
        ev = ev > 0.f ? ev : SLOPE * ev;
        float w = __expf(ev);
        int pos = atomicAdd(&lcur[dl], 1);
        wcsr[r0 + loff[dl] + pos] =
            (unsigned)s | ((unsigned)__half_as_ushort(__float2half(w)) << 16);
    }
}

// ---------------- gather: wave/dst, 4 edge-streams (q=lane>>4), 4 features/lane ----------------
__global__ __launch_bounds__(256) void gather_kernel(const unsigned* __restrict__ wcsr,
                                                     const int* __restrict__ offsets,
                                                     const int* __restrict__ counts,
                                                     const __half* __restrict__ xp,
                                                     const float* __restrict__ bias,
                                                     float* __restrict__ out) {
    __shared__ unsigned stage[4][64];
    int wave = threadIdx.x >> 6, lane = threadIdx.x & 63;
    int d = blockIdx.x * 4 + wave;
    if (d >= N_NODES) return;
    int start = offsets[d], cnt = counts[d];
    int q = lane >> 4, f = lane & 15;
    const uint2* xp2 = (const uint2*)xp;      // 8 B = 4 halves
    float4 acc = make_float4(0.f, 0.f, 0.f, 0.f);
    float ws = 0.f;

    for (int jb = 0; jb < cnt; jb += 64) {
        int iters = min(cnt - jb, 64);
        unsigned rc = (lane < iters) ? wcsr[start + jb + lane] : 0u;
        stage[wave][lane] = rc;               // wave-private; in-order within wave
        int m = (iters - q + 3) >> 2;         // this quarter's edge count
        unsigned u = stage[wave][q];
        uint2 hv = xp2[(u & 0xFFFFu) * 16 + f];
        for (int i = 0; i < m; ++i) {
            unsigned u_cur = u;
            uint2 hv_cur = hv;
            if (i + 1 < m) {                  // prefetch next edge (exec-masked)
                u = stage[wave][q + (i + 1) * 4];
                hv = xp2[(u & 0xFFFFu) * 16 + f];
            }
            float w = __half2float(__ushort_as_half((unsigned short)(u_cur >> 16)));
            __half2 h0 = __builtin_bit_cast(__half2, hv_cur.x);
            __half2 h1 = __builtin_bit_cast(__half2, hv_cur.y);
            float2 f0 = __half22float2(h0);
            float2 f1 = __half22float2(h1);
            acc.x = fmaf(w, f0.x, acc.x);
            acc.y = fmaf(w, f0.y, acc.y);
            acc.z = fmaf(w, f1.x, acc.z);
            acc.w = fmaf(w, f1.y, acc.w);
            ws += w;
        }
    }
    // reduce across the 4 quarters
#pragma unroll
    for (int off = 16; off < 64; off <<= 1) {
        acc.x += __shfl_xor(acc.x, off);
        acc.y += __shfl_xor(acc.y, off);
        acc.z += __shfl_xor(acc.z, off);
        acc.w += __shfl_xor(acc.w, off);
        ws    += __shfl_xor(ws, off);
    }
    if (q == 0) {
        float inv = 1.f / ws;
        float4 bl = ((const float4*)bias)[f];
        float4 o;
        o.x = fmaf(acc.x, inv, bl.x);
        o.y = fmaf(acc.y, inv, bl.y);
        o.z = fmaf(acc.z, inv, bl.z);
        o.w = fmaf(acc.w, inv, bl.w);
        o.x = o.x > 0.f ? o.x : 0.f;
        o.y = o.y > 0.f ? o.y : 0.f;
        o.z = o.z > 0.f ? o.z : 0.f;
        o.w = o.w > 0.f ? o.w : 0.f;
        ((float4*)out)[(size_t)d * 16 + f] = o;
    }
}

extern "C" void kernel_launch(void* const* d_in, const int* in_sizes, int n_in,
                              void* d_out, int out_size, void* d_ws, size_t ws_size,
                              hipStream_t stream) {
    const float* x     = (const float*)d_in[0];
    const float* W     = (const float*)d_in[1];
    const float* a_src = (const float*)d_in[2];
    const float* a_dst = (const float*)d_in[3];
    const float* bias  = (const float*)d_in[4];
    const int*   ei    = (const int*)d_in[5];
    float* out = (float*)d_out;

    _Float16* xph   = (_Float16*)d_ws;                        // N*64 fp16
    float*  as      = (float*)(xph + (size_t)N_NODES * F_OUT);
    float*  ad      = as + N_NODES;
    int*    counts  = (int*)(ad + N_NODES);                   // N
    int*    offsets = counts + N_NODES;                       // N
    int*    bcur    = offsets + N_NODES;                      // NBUCK
    unsigned* rec   = (unsigned*)(bcur + NBUCK + 64);         // NBUCK*CAP u32
    unsigned* wcsr  = rec + (size_t)NBUCK * CAP;              // NBUCK*CAP u32

    gemm_kernel<<<(N_NODES + 63) / 64, 256, 0, stream>>>(
        (const float4*)x, (const float4*)W, a_src, a_dst, xph, as, ad, bcur);
    part_kernel<<<PBLOCKS, 256, 0, stream>>>(ei, bcur, rec);
    csrb_kernel<<<NBUCK, 512, 0, stream>>>(rec, bcur, as, ad, offsets, counts, wcsr);
    gather_kernel<<<(N_NODES + 3) / 4, 256, 0, stream>>>(wcsr, offsets, counts,
                                                         (const __half*)xph, bias, out);
}

// Round 8
// 93.816 us; speedup vs baseline: 1.1269x; 1.1269x over previous
//
#include <hip/hip_runtime.h>
#include <hip/hip_fp16.h>
#include <math.h>

#define N_NODES 50000
#define N_EDGES 1600000
#define ET (N_EDGES + N_NODES)
#define F_OUT 64
#define F_IN 128
#define SLOPE 0.2f
#define BSHIFT 7                               // 128 nodes per bucket
#define BNODES 128
#define NBUCK ((N_NODES + BNODES - 1) >> BSHIFT)   // 391 buckets
#define CAP 4736                               // mean 4224 + 8 sigma
#define EPB 4096                               // edges per partition block
#define PBLOCKS ((ET + EPB - 1) / EPB)         // 403

typedef _Float16 half8 __attribute__((ext_vector_type(8)));
typedef _Float16 half4 __attribute__((ext_vector_type(4)));
typedef float f32x4 __attribute__((ext_vector_type(4)));

// ---------------- MFMA GEMM: xp(f16) = x @ W + attention logits (+bcur zero) ----------------
__global__ __launch_bounds__(256) void gemm_kernel(const float4* __restrict__ x4,
                                                   const float4* __restrict__ W4,
                                                   const float* __restrict__ a_src,
                                                   const float* __restrict__ a_dst,
                                                   _Float16* __restrict__ xph,
                                                   float* __restrict__ alpha_s,
                                                   float* __restrict__ alpha_d,
                                                   int* __restrict__ bcur) {
    __shared__ _Float16 xs[64][136];          // padded: row stride 272B
    __shared__ float    Wsh[F_IN * F_OUT];    // 32 KB
    int t = threadIdx.x;
    if (blockIdx.x == 0)
        for (int i = t; i < NBUCK; i += 256) bcur[i] = 0;
    int wave = t >> 6, lane = t & 63;
    int g = lane >> 4, c16 = lane & 15;

#pragma unroll
    for (int i = 0; i < 8; ++i)
        ((float4*)Wsh)[t + i * 256] = W4[t + i * 256];
    size_t rbase = (size_t)blockIdx.x * 64;
#pragma unroll
    for (int i = 0; i < 8; ++i) {
        int idx = t + i * 256;                 // over 64*32 float4
        int row = idx >> 5, c4 = idx & 31;
        size_t gr = rbase + row;
        if (gr >= N_NODES) gr = N_NODES - 1;
        float4 v = x4[gr * (F_IN / 4) + c4];
        half4 hv = { (_Float16)v.x, (_Float16)v.y, (_Float16)v.z, (_Float16)v.w };
        *(half4*)&xs[row][c4 * 4] = hv;
    }
    __syncthreads();

    half8 bw[4][4];
#pragma unroll
    for (int nt = 0; nt < 4; ++nt)
#pragma unroll
        for (int kt = 0; kt < 4; ++kt) {
            int col = nt * 16 + c16;
            int k0 = kt * 32 + g * 8;
#pragma unroll
            for (int e = 0; e < 8; ++e)
                bw[nt][kt][e] = (_Float16)Wsh[(k0 + e) * F_OUT + col];
        }

    int r0 = wave * 16;
    half8 af[4];
#pragma unroll
    for (int kt = 0; kt < 4; ++kt)
        af[kt] = *(const half8*)&xs[r0 + c16][kt * 32 + g * 8];

    f32x4 acc[4];
#pragma unroll
    for (int nt = 0; nt < 4; ++nt) {
        acc[nt] = (f32x4){0.f, 0.f, 0.f, 0.f};
#pragma unroll
        for (int kt = 0; kt < 4; ++kt)
            acc[nt] = __builtin_amdgcn_mfma_f32_16x16x32_f16(af[kt], bw[nt][kt], acc[nt], 0, 0, 0);
    }

    int growbase = (int)rbase + r0 + g * 4;
#pragma unroll
    for (int nt = 0; nt < 4; ++nt) {
#pragma unroll
        for (int r = 0; r < 4; ++r) {
            int row = growbase + r;
            if (row < N_NODES)
                xph[(size_t)row * F_OUT + nt * 16 + c16] = (_Float16)acc[nt][r];
        }
    }
    float asl[4], adl[4];
#pragma unroll
    for (int nt = 0; nt < 4; ++nt) {
        asl[nt] = a_src[nt * 16 + c16];
        adl[nt] = a_dst[nt * 16 + c16];
    }
#pragma unroll
    for (int r = 0; r < 4; ++r) {
        float ps = 0.f, pd = 0.f;
#pragma unroll
        for (int nt = 0; nt < 4; ++nt) {
            ps = fmaf(acc[nt][r], asl[nt], ps);
            pd = fmaf(acc[nt][r], adl[nt], pd);
        }
#pragma unroll
        for (int off = 1; off < 16; off <<= 1) {
            ps += __shfl_xor(ps, off);
            pd += __shfl_xor(pd, off);
        }
        int row = growbase + r;
        if (c16 == 0 && row < N_NODES) { alpha_s[row] = ps; alpha_d[row] = pd; }
    }
}

// ---------------- partition: single-pass rank capture, 16 edges/thread ----------------
__global__ __launch_bounds__(256) void part_kernel(const int* __restrict__ ei,
                                                   int* __restrict__ bcur,
                                                   unsigned* __restrict__ rec) {
    __shared__ int lc[NBUCK];
    __shared__ int lbase[NBUCK];
    int t = threadIdx.x;
    for (int b = t; b < NBUCK; b += 256) lc[b] = 0;
    __syncthreads();
    int e0 = blockIdx.x * EPB;

    unsigned u[16]; short bk[16]; unsigned short rk[16];
#pragma unroll
    for (int k = 0; k < 4; ++k) {
        int e = e0 + k * 1024 + t * 4;
        int4 sv, dv;
        if (e + 3 < N_EDGES) {                 // fast path: 16B aligned vector loads
            sv = *(const int4*)&ei[e];
            dv = *(const int4*)&ei[N_EDGES + e];
        } else {
            int* sp = (int*)&sv; int* dp = (int*)&dv;
#pragma unroll
            for (int j = 0; j < 4; ++j) {
                int ee = e + j;
                if (ee < N_EDGES)      { sp[j] = ei[ee]; dp[j] = ei[N_EDGES + ee]; }
                else if (ee < ET)      { sp[j] = dp[j] = ee - N_EDGES; }
                else                   { sp[j] = dp[j] = -1; }
            }
        }
        const int* sp = (const int*)&sv; const int* dp = (const int*)&dv;
#pragma unroll
        for (int j = 0; j < 4; ++j) {
            int i = k * 4 + j;
            int d = dp[j];
            if (d >= 0) {
                int b = d >> BSHIFT;
                bk[i] = (short)b;
                rk[i] = (unsigned short)atomicAdd(&lc[b], 1);
                u[i] = (unsigned)sp[j] | ((unsigned)d << 16);
            } else bk[i] = -1;
        }
    }
    __syncthreads();
    for (int b = t; b < NBUCK; b += 256)
        lbase[b] = lc[b] ? (b * CAP + atomicAdd(&bcur[b], lc[b])) : 0;
    __syncthreads();
#pragma unroll
    for (int i = 0; i < 16; ++i)
        if (bk[i] >= 0) rec[lbase[bk[i]] + rk[i]] = u[i];
}

// ---------------- scan helper (8 waves) ----------------
__device__ __forceinline__ int block_incl_scan(int v, int t, int* wsum) {
    int lane = t & 63, wave = t >> 6;
#pragma unroll
    for (int off = 1; off < 64; off <<= 1) {
        int n = __shfl_up(v, off);
        if (lane >= off) v += n;
    }
    if (lane == 63) wsum[wave] = v;
    __syncthreads();
    int add = 0;
    for (int w = 0; w < wave; ++w) add += wsum[w];
    return v + add;
}

// ---------------- per-bucket CSR build + edge-weight precompute ----------------
__global__ __launch_bounds__(512) void csrb_kernel(const unsigned* __restrict__ rec,
                                                   const int* __restrict__ bcur,
                                                   const float* __restrict__ as,
                                                   const float* __restrict__ ad,
                                                   int* __restrict__ offsets,
                                                   int* __restrict__ counts,
                                                   unsigned* __restrict__ wcsr) {
    __shared__ unsigned lrec[CAP];            // 18.9 KB
    __shared__ int lcnt[BNODES], loff[BNODES], lcur[BNODES];
    __shared__ float adl[BNODES];
    __shared__ int wsum[8];
    int t = threadIdx.x;
    int b = blockIdx.x;
    int n0 = b << BSHIFT;
    int r0 = b * CAP;
    int cnt_b = bcur[b];
    if (t < BNODES) {
        lcnt[t] = 0; lcur[t] = 0;
        adl[t] = (n0 + t < N_NODES) ? ad[n0 + t] : 0.f;
    }
    for (int i = t; i < cnt_b; i += 512) lrec[i] = rec[r0 + i];
    __syncthreads();
    for (int i = t; i < cnt_b; i += 512)
        atomicAdd(&lcnt[(lrec[i] >> 16) & (BNODES - 1)], 1);
    __syncthreads();
    int v = (t < BNODES) ? lcnt[t] : 0;
    int incl = block_incl_scan(v, t, wsum);
    if (t < BNODES) {
        loff[t] = incl - v;
        if (n0 + t < N_NODES) { counts[n0 + t] = v; offsets[n0 + t] = r0 + incl - v; }
    }
    __syncthreads();
    for (int i = t; i < cnt_b; i += 512) {
        unsigned u = lrec[i];
        int dl = (u >> 16) & (BNODES - 1);
        int s = u & 0xFFFFu;
        float ev = as[s] + adl[dl];
        ev = ev > 0.f ? ev : SLOPE * ev;
        float w = __expf(ev);
        int pos = atomicAdd(&lcur[dl], 1);
        wcsr[r0 + loff[dl] + pos] =
            (unsigned)s | ((unsigned)__half_as_ushort(__float2half(w)) << 16);
    }
}

// ---------------- gather: wave/dst, 4 edge-streams (q=lane>>4), 4 features/lane ----------------
__global__ __launch_bounds__(256) void gather_kernel(const unsigned* __restrict__ wcsr,
                                                     const int* __restrict__ offsets,
                                                     const int* __restrict__ counts,
                                                     const __half* __restrict__ xp,
                                                     const float* __restrict__ bias,
                                                     float* __restrict__ out) {
    __shared__ unsigned stage[4][64];
    int wave = threadIdx.x >> 6, lane = threadIdx.x & 63;
    int d = blockIdx.x * 4 + wave;
    if (d >= N_NODES) return;
    int start = offsets[d], cnt = counts[d];
    int q = lane >> 4, f = lane & 15;
    const uint2* xp2 = (const uint2*)xp;
    float4 acc = make_float4(0.f, 0.f, 0.f, 0.f);
    float ws = 0.f;

    for (int jb = 0; jb < cnt; jb += 64) {
        int iters = min(cnt - jb, 64);
        unsigned rc = (lane < iters) ? wcsr[start + jb + lane] : 0u;
        stage[wave][lane] = rc;
        int m = (iters - q + 3) >> 2;
        unsigned u = stage[wave][q];
        uint2 hv = xp2[(u & 0xFFFFu) * 16 + f];
        for (int i = 0; i < m; ++i) {
            unsigned u_cur = u;
            uint2 hv_cur = hv;
            if (i + 1 < m) {
                u = stage[wave][q + (i + 1) * 4];
                hv = xp2[(u & 0xFFFFu) * 16 + f];
            }
            float w = __half2float(__ushort_as_half((unsigned short)(u_cur >> 16)));
            __half2 h0 = __builtin_bit_cast(__half2, hv_cur.x);
            __half2 h1 = __builtin_bit_cast(__half2, hv_cur.y);
            float2 f0 = __half22float2(h0);
            float2 f1 = __half22float2(h1);
            acc.x = fmaf(w, f0.x, acc.x);
            acc.y = fmaf(w, f0.y, acc.y);
            acc.z = fmaf(w, f1.x, acc.z);
            acc.w = fmaf(w, f1.y, acc.w);
            ws += w;
        }
    }
#pragma unroll
    for (int off = 16; off < 64; off <<= 1) {
        acc.x += __shfl_xor(acc.x, off);
        acc.y += __shfl_xor(acc.y, off);
        acc.z += __shfl_xor(acc.z, off);
        acc.w += __shfl_xor(acc.w, off);
        ws    += __shfl_xor(ws, off);
    }
    if (q == 0) {
        float inv = 1.f / ws;
        float4 bl = ((const float4*)bias)[f];
        float4 o;
        o.x = fmaf(acc.x, inv, bl.x);
        o.y = fmaf(acc.y, inv, bl.y);
        o.z = fmaf(acc.z, inv, bl.z);
        o.w = fmaf(acc.w, inv, bl.w);
        o.x = o.x > 0.f ? o.x : 0.f;
        o.y = o.y > 0.f ? o.y : 0.f;
        o.z = o.z > 0.f ? o.z : 0.f;
        o.w = o.w > 0.f ? o.w : 0.f;
        ((float4*)out)[(size_t)d * 16 + f] = o;
    }
}

extern "C" void kernel_launch(void* const* d_in, const int* in_sizes, int n_in,
                              void* d_out, int out_size, void* d_ws, size_t ws_size,
                              hipStream_t stream) {
    const float* x     = (const float*)d_in[0];
    const float* W     = (const float*)d_in[1];
    const float* a_src = (const float*)d_in[2];
    const float* a_dst = (const float*)d_in[3];
    const float* bias  = (const float*)d_in[4];
    const int*   ei    = (const int*)d_in[5];
    float* out = (float*)d_out;

    _Float16* xph   = (_Float16*)d_ws;                        // N*64 fp16
    float*  as      = (float*)(xph + (size_t)N_NODES * F_OUT);
    float*  ad      = as + N_NODES;
    int*    counts  = (int*)(ad + N_NODES);                   // N
    int*    offsets = counts + N_NODES;                       // N
    int*    bcur    = offsets + N_NODES;                      // NBUCK
    unsigned* rec   = (unsigned*)(bcur + NBUCK + 64);         // NBUCK*CAP u32
    unsigned* wcsr  = rec + (size_t)NBUCK * CAP;              // NBUCK*CAP u32

    gemm_kernel<<<(N_NODES + 63) / 64, 256, 0, stream>>>(
        (const float4*)x, (const float4*)W, a_src, a_dst, xph, as, ad, bcur);
    part_kernel<<<PBLOCKS, 256, 0, stream>>>(ei, bcur, rec);
    csrb_kernel<<<NBUCK, 512, 0, stream>>>(rec, bcur, as, ad, offsets, counts, wcsr);
    gather_kernel<<<(N_NODES + 3) / 4, 256, 0, stream>>>(wcsr, offsets, counts,
                                                         (const __half*)xph, bias, out);
}

// Round 9
// 85.841 us; speedup vs baseline: 1.2316x; 1.0929x over previous
//
#include <hip/hip_runtime.h>
#include <hip/hip_fp16.h>
#include <math.h>

#define N_NODES 50000
#define N_EDGES 1600000
#define ET (N_EDGES + N_NODES)
#define F_OUT 64
#define F_IN 128
#define SLOPE 0.2f
#define BSHIFT 7                               // 128 nodes per bucket
#define BNODES 128
#define NBUCK ((N_NODES + BNODES - 1) >> BSHIFT)   // 391 buckets
#define CAP 4736                               // mean 4224 + 8 sigma
#define EPB 4096                               // edges per partition block
#define PBLOCKS ((ET + EPB - 1) / EPB)         // 403

typedef _Float16 half8 __attribute__((ext_vector_type(8)));
typedef _Float16 half4 __attribute__((ext_vector_type(4)));
typedef float f32x4 __attribute__((ext_vector_type(4)));

// ---------------- MFMA GEMM: xp(f16) = x @ W + attention logits (+bcur zero) ----------------
__global__ __launch_bounds__(256) void gemm_kernel(const float4* __restrict__ x4,
                                                   const float4* __restrict__ W4,
                                                   const float* __restrict__ a_src,
                                                   const float* __restrict__ a_dst,
                                                   _Float16* __restrict__ xph,
                                                   float* __restrict__ alpha_s,
                                                   float* __restrict__ alpha_d,
                                                   int* __restrict__ bcur) {
    __shared__ _Float16 xs[64][136];          // padded: row stride 272B
    __shared__ float    Wsh[F_IN * F_OUT];    // 32 KB
    int t = threadIdx.x;
    if (blockIdx.x == 0)
        for (int i = t; i < NBUCK; i += 256) bcur[i] = 0;
    int wave = t >> 6, lane = t & 63;
    int g = lane >> 4, c16 = lane & 15;

#pragma unroll
    for (int i = 0; i < 8; ++i)
        ((float4*)Wsh)[t + i * 256] = W4[t + i * 256];
    size_t rbase = (size_t)blockIdx.x * 64;
#pragma unroll
    for (int i = 0; i < 8; ++i) {
        int idx = t + i * 256;                 // over 64*32 float4
        int row = idx >> 5, c4 = idx & 31;
        size_t gr = rbase + row;
        if (gr >= N_NODES) gr = N_NODES - 1;
        float4 v = x4[gr * (F_IN / 4) + c4];
        half4 hv = { (_Float16)v.x, (_Float16)v.y, (_Float16)v.z, (_Float16)v.w };
        *(half4*)&xs[row][c4 * 4] = hv;
    }
    __syncthreads();

    half8 bw[4][4];
#pragma unroll
    for (int nt = 0; nt < 4; ++nt)
#pragma unroll
        for (int kt = 0; kt < 4; ++kt) {
            int col = nt * 16 + c16;
            int k0 = kt * 32 + g * 8;
#pragma unroll
            for (int e = 0; e < 8; ++e)
                bw[nt][kt][e] = (_Float16)Wsh[(k0 + e) * F_OUT + col];
        }

    int r0 = wave * 16;
    half8 af[4];
#pragma unroll
    for (int kt = 0; kt < 4; ++kt)
        af[kt] = *(const half8*)&xs[r0 + c16][kt * 32 + g * 8];

    f32x4 acc[4];
#pragma unroll
    for (int nt = 0; nt < 4; ++nt) {
        acc[nt] = (f32x4){0.f, 0.f, 0.f, 0.f};
#pragma unroll
        for (int kt = 0; kt < 4; ++kt)
            acc[nt] = __builtin_amdgcn_mfma_f32_16x16x32_f16(af[kt], bw[nt][kt], acc[nt], 0, 0, 0);
    }

    int growbase = (int)rbase + r0 + g * 4;
#pragma unroll
    for (int nt = 0; nt < 4; ++nt) {
#pragma unroll
        for (int r = 0; r < 4; ++r) {
            int row = growbase + r;
            if (row < N_NODES)
                xph[(size_t)row * F_OUT + nt * 16 + c16] = (_Float16)acc[nt][r];
        }
    }
    float asl[4], adl[4];
#pragma unroll
    for (int nt = 0; nt < 4; ++nt) {
        asl[nt] = a_src[nt * 16 + c16];
        adl[nt] = a_dst[nt * 16 + c16];
    }
#pragma unroll
    for (int r = 0; r < 4; ++r) {
        float ps = 0.f, pd = 0.f;
#pragma unroll
        for (int nt = 0; nt < 4; ++nt) {
            ps = fmaf(acc[nt][r], asl[nt], ps);
            pd = fmaf(acc[nt][r], adl[nt], pd);
        }
#pragma unroll
        for (int off = 1; off < 16; off <<= 1) {
            ps += __shfl_xor(ps, off);
            pd += __shfl_xor(pd, off);
        }
        int row = growbase + r;
        if (c16 == 0 && row < N_NODES) { alpha_s[row] = ps; alpha_d[row] = pd; }
    }
}

// ---------------- partition: single-pass rank capture, 16 edges/thread ----------------
__global__ __launch_bounds__(256) void part_kernel(const int* __restrict__ ei,
                                                   int* __restrict__ bcur,
                                                   unsigned* __restrict__ rec) {
    __shared__ int lc[NBUCK];
    __shared__ int lbase[NBUCK];
    int t = threadIdx.x;
    for (int b = t; b < NBUCK; b += 256) lc[b] = 0;
    __syncthreads();
    int e0 = blockIdx.x * EPB;

    unsigned u[16]; short bk[16]; unsigned short rk[16];
#pragma unroll
    for (int k = 0; k < 4; ++k) {
        int e = e0 + k * 1024 + t * 4;
        int4 sv, dv;
        if (e + 3 < N_EDGES) {                 // fast path: 16B aligned vector loads
            sv = *(const int4*)&ei[e];
            dv = *(const int4*)&ei[N_EDGES + e];
        } else {
            int* sp = (int*)&sv; int* dp = (int*)&dv;
#pragma unroll
            for (int j = 0; j < 4; ++j) {
                int ee = e + j;
                if (ee < N_EDGES)      { sp[j] = ei[ee]; dp[j] = ei[N_EDGES + ee]; }
                else if (ee < ET)      { sp[j] = dp[j] = ee - N_EDGES; }
                else                   { sp[j] = dp[j] = -1; }
            }
        }
        const int* sp = (const int*)&sv; const int* dp = (const int*)&dv;
#pragma unroll
        for (int j = 0; j < 4; ++j) {
            int i = k * 4 + j;
            int d = dp[j];
            if (d >= 0) {
                int b = d >> BSHIFT;
                bk[i] = (short)b;
                rk[i] = (unsigned short)atomicAdd(&lc[b], 1);
                u[i] = (unsigned)sp[j] | ((unsigned)d << 16);
            } else bk[i] = -1;
        }
    }
    __syncthreads();
    for (int b = t; b < NBUCK; b += 256)
        lbase[b] = lc[b] ? (b * CAP + atomicAdd(&bcur[b], lc[b])) : 0;
    __syncthreads();
#pragma unroll
    for (int i = 0; i < 16; ++i)
        if (bk[i] >= 0) rec[lbase[bk[i]] + rk[i]] = u[i];
}

// ---------------- scan helper (8 waves) ----------------
__device__ __forceinline__ int block_incl_scan(int v, int t, int* wsum) {
    int lane = t & 63, wave = t >> 6;
#pragma unroll
    for (int off = 1; off < 64; off <<= 1) {
        int n = __shfl_up(v, off);
        if (lane >= off) v += n;
    }
    if (lane == 63) wsum[wave] = v;
    __syncthreads();
    int add = 0;
    for (int w = 0; w < wave; ++w) add += wsum[w];
    return v + add;
}

// ---------------- per-bucket CSR build + edge-weight precompute ----------------
__global__ __launch_bounds__(512) void csrb_kernel(const unsigned* __restrict__ rec,
                                                   const int* __restrict__ bcur,
                                                   const float* __restrict__ as,
                                                   const float* __restrict__ ad,
                                                   int* __restrict__ offsets,
                                                   int* __restrict__ counts,
                                                   unsigned* __restrict__ wcsr) {
    __shared__ unsigned lrec[CAP];            // 18.9 KB
    __shared__ int lcnt[BNODES], loff[BNODES], lcur[BNODES];
    __shared__ float adl[BNODES];
    __shared__ int wsum[8];
    int t = threadIdx.x;
    int b = blockIdx.x;
    int n0 = b << BSHIFT;
    int r0 = b * CAP;
    int cnt_b = bcur[b];
    if (t < BNODES) {
        lcnt[t] = 0; lcur[t] = 0;
        adl[t] = (n0 + t < N_NODES) ? ad[n0 + t] : 0.f;
    }
    for (int i = t; i < cnt_b; i += 512) lrec[i] = rec[r0 + i];
    __syncthreads();
    for (int i = t; i < cnt_b; i += 512)
        atomicAdd(&lcnt[(lrec[i] >> 16) & (BNODES - 1)], 1);
    __syncthreads();
    int v = (t < BNODES) ? lcnt[t] : 0;
    int incl = block_incl_scan(v, t, wsum);
    if (t < BNODES) {
        loff[t] = incl - v;
        if (n0 + t < N_NODES) { counts[n0 + t] = v; offsets[n0 + t] = r0 + incl - v; }
    }
    __syncthreads();
    for (int i = t; i < cnt_b; i += 512) {
        unsigned u = lrec[i];
        int dl = (u >> 16) & (BNODES - 1);
        int s = u & 0xFFFFu;
        float ev = as[s] + adl[dl];
        ev = ev > 0.f ? ev : SLOPE * ev;
        float w = __expf(ev);
        int pos = atomicAdd(&lcur[dl], 1);
        wcsr[r0 + loff[dl] + pos] =
            (unsigned)s | ((unsigned)__half_as_ushort(__float2half(w)) << 16);
    }
}

// ---------------- gather: wave/dst, 4 edge-streams, depth-4 software pipeline ----------------
#define CONSUME(u_, h_)                                                        \
    {                                                                          \
        float w = __half2float(__ushort_as_half((unsigned short)((u_) >> 16)));\
        float2 f0 = __half22float2(__builtin_bit_cast(__half2, (h_).x));       \
        float2 f1 = __half22float2(__builtin_bit_cast(__half2, (h_).y));       \
        acc.x = fmaf(w, f0.x, acc.x);                                          \
        acc.y = fmaf(w, f0.y, acc.y);                                          \
        acc.z = fmaf(w, f1.x, acc.z);                                          \
        acc.w = fmaf(w, f1.y, acc.w);                                          \
        ws += w;                                                               \
    }

__global__ __launch_bounds__(256) void gather_kernel(const unsigned* __restrict__ wcsr,
                                                     const int* __restrict__ offsets,
                                                     const int* __restrict__ counts,
                                                     const __half* __restrict__ xp,
                                                     const float* __restrict__ bias,
                                                     float* __restrict__ out) {
    __shared__ unsigned stage[4][64];
    int wave = threadIdx.x >> 6, lane = threadIdx.x & 63;
    int d = blockIdx.x * 4 + wave;
    if (d >= N_NODES) return;
    int start = offsets[d], cnt = counts[d];
    int q = lane >> 4, f = lane & 15;
    const uint2* xp2 = (const uint2*)xp;
    float4 acc = make_float4(0.f, 0.f, 0.f, 0.f);
    float ws = 0.f;

    for (int jb = 0; jb < cnt; jb += 64) {
        int iters = min(cnt - jb, 64);
        unsigned rc = (lane < iters) ? wcsr[start + jb + lane] : 0u;
        stage[wave][lane] = rc;               // wave-private; lanes >= iters write 0
        int m = (iters - q + 3) >> 2;         // this quarter's edge count
        int M4 = (m + 3) & ~3;                // rounded up; extras have u=0 -> w=0
        // prime the pipeline: 4 rows in flight
        unsigned u0 = stage[wave][q];
        unsigned u1 = stage[wave][q + 4];
        unsigned u2 = stage[wave][q + 8];
        unsigned u3 = stage[wave][q + 12];
        uint2 h0 = xp2[(u0 & 0xFFFFu) * 16 + f];
        uint2 h1 = xp2[(u1 & 0xFFFFu) * 16 + f];
        uint2 h2 = xp2[(u2 & 0xFFFFu) * 16 + f];
        uint2 h3 = xp2[(u3 & 0xFFFFu) * 16 + f];
        for (int i = 0; i < M4; i += 4) {
            CONSUME(u0, h0);
            if (i + 4 < M4) { u0 = stage[wave][q + (i + 4) * 4];
                              h0 = xp2[(u0 & 0xFFFFu) * 16 + f]; }
            CONSUME(u1, h1);
            if (i + 5 < M4) { u1 = stage[wave][q + (i + 5) * 4];
                              h1 = xp2[(u1 & 0xFFFFu) * 16 + f]; }
            CONSUME(u2, h2);
            if (i + 6 < M4) { u2 = stage[wave][q + (i + 6) * 4];
                              h2 = xp2[(u2 & 0xFFFFu) * 16 + f]; }
            CONSUME(u3, h3);
            if (i + 7 < M4) { u3 = stage[wave][q + (i + 7) * 4];
                              h3 = xp2[(u3 & 0xFFFFu) * 16 + f]; }
        }
    }
#pragma unroll
    for (int off = 16; off < 64; off <<= 1) {
        acc.x += __shfl_xor(acc.x, off);
        acc.y += __shfl_xor(acc.y, off);
        acc.z += __shfl_xor(acc.z, off);
        acc.w += __shfl_xor(acc.w, off);
        ws    += __shfl_xor(ws, off);
    }
    if (q == 0) {
        float inv = 1.f / ws;
        float4 bl = ((const float4*)bias)[f];
        float4 o;
        o.x = fmaf(acc.x, inv, bl.x);
        o.y = fmaf(acc.y, inv, bl.y);
        o.z = fmaf(acc.z, inv, bl.z);
        o.w = fmaf(acc.w, inv, bl.w);
        o.x = o.x > 0.f ? o.x : 0.f;
        o.y = o.y > 0.f ? o.y : 0.f;
        o.z = o.z > 0.f ? o.z : 0.f;
        o.w = o.w > 0.f ? o.w : 0.f;
        ((float4*)out)[(size_t)d * 16 + f] = o;
    }
}

extern "C" void kernel_launch(void* const* d_in, const int* in_sizes, int n_in,
                              void* d_out, int out_size, void* d_ws, size_t ws_size,
                              hipStream_t stream) {
    const float* x     = (const float*)d_in[0];
    const float* W     = (const float*)d_in[1];
    const float* a_src = (const float*)d_in[2];
    const float* a_dst = (const float*)d_in[3];
    const float* bias  = (const float*)d_in[4];
    const int*   ei    = (const int*)d_in[5];
    float* out = (float*)d_out;

    _Float16* xph   = (_Float16*)d_ws;                        // N*64 fp16
    float*  as      = (float*)(xph + (size_t)N_NODES * F_OUT);
    float*  ad      = as + N_NODES;
    int*    counts  = (int*)(ad + N_NODES);                   // N
    int*    offsets = counts + N_NODES;                       // N
    int*    bcur    = offsets + N_NODES;                      // NBUCK
    unsigned* rec   = (unsigned*)(bcur + NBUCK + 64);         // NBUCK*CAP u32
    unsigned* wcsr  = rec + (size_t)NBUCK * CAP;              // NBUCK*CAP u32

    gemm_kernel<<<(N_NODES + 63) / 64, 256, 0, stream>>>(
        (const float4*)x, (const float4*)W, a_src, a_dst, xph, as, ad, bcur);
    part_kernel<<<PBLOCKS, 256, 0, stream>>>(ei, bcur, rec);
    csrb_kernel<<<NBUCK, 512, 0, stream>>>(rec, bcur, as, ad, offsets, counts, wcsr);
    gather_kernel<<<(N_NODES + 3) / 4, 256, 0, stream>>>(wcsr, offsets, counts,
                                                         (const __half*)xph, bias, out);
}